// Round 2
// baseline (122.075 us; speedup 1.0000x reference)
//
#include <hip/hip_runtime.h>

// ASTGC_37976100831379
//
// The reference's fusion GCN is a star graph with edges 0 -> 1..N only, so
// node 0 receives NO messages. The returned slice fusion_out[:, 0] is
// zeros + fgcn_b broadcast over batch:
//     out[b, s] = fgcn_b[s]     (B=32, S=48)
// All upstream work (TCNs, fusion GEMMs, GCN aggregation, attention) is dead
// code w.r.t. the output. Kernel = broadcast copy of input 30 (fgcn_b).
//
// DTYPE: the reference is float32 end-to-end (jnp.float32), so all buffers
// are float* (round-1 failure was caused by treating them as bf16: half the
// fp32 output buffer was left at zero, reproducing the zero-output absmax).

#define S_LEN 48

__global__ void astgc_broadcast_bias(const float* __restrict__ fgcn_b,
                                     float* __restrict__ out,
                                     int total) {
    int i = blockIdx.x * blockDim.x + threadIdx.x;
    if (i < total) {
        out[i] = fgcn_b[i % S_LEN];
    }
}

extern "C" void kernel_launch(void* const* d_in, const int* in_sizes, int n_in,
                              void* d_out, int out_size, void* d_ws, size_t ws_size,
                              hipStream_t stream) {
    // setup_inputs order: index 30 == fgcn_b (S,) float32
    const float* fgcn_b = (const float*)d_in[30];
    float* out = (float*)d_out;

    const int total = out_size;  // B * S * 1 = 1536
    const int block = 256;
    const int grid = (total + block - 1) / block;
    astgc_broadcast_bias<<<grid, block, 0, stream>>>(fgcn_b, out, total);
}